// Round 12
// baseline (185.759 us; speedup 1.0000x reference)
//
#include <hip/hip_runtime.h>
#include <math.h>

#define T_ 128
#define B_ 512
#define S_ 128
#define D_ 128
#define V_ 50257

#define K2_VT 64
#define K2_NB ((V_ + K2_VT - 1) / K2_VT)   // 786

// ---------------- k1f: fused {M2 = transform @ tag_embed^T} and {A = softmax(tparams)} ----
__global__ __launch_bounds__(128) void k1_fused(const float* __restrict__ transform,
                                                const float* __restrict__ tag_embed,
                                                const float* __restrict__ tparams,
                                                float* __restrict__ M2,
                                                float* __restrict__ A) {
  int tid = threadIdx.x;
  int bid = blockIdx.x;
  if (bid < 128) {
    __shared__ float te[128][129];
    for (int r = 0; r < 128; ++r) te[r][tid] = tag_embed[r * 128 + tid];
    __syncthreads();
    int k = bid;
    float acc = 0.f;
    #pragma unroll 8
    for (int d = 0; d < 128; ++d) acc += transform[k * 128 + d] * te[tid][d];
    M2[k * 128 + tid] = acc;
  } else {
    if (tid < 64) {
      int i = bid - 128;
      int l = tid;
      float x0 = tparams[i * 128 + l];
      float x1 = tparams[i * 128 + 64 + l];
      float m = fmaxf(x0, x1);
      #pragma unroll
      for (int off = 32; off; off >>= 1) m = fmaxf(m, __shfl_xor(m, off));
      float e0 = __expf(x0 - m), e1 = __expf(x1 - m);
      float s = e0 + e1;
      #pragma unroll
      for (int off = 32; off; off >>= 1) s += __shfl_xor(s, off);
      float inv = 1.f / s;
      A[i * 128 + l]      = e0 * inv;
      A[i * 128 + 64 + l] = e1 * inv;
    }
  }
}

// ---------------- k2: logits = we @ M2 + corr^T, fused col-softmax partials ----------------
// (round-8 v2: no weT tile, m2t-only LDS, 4 blocks/CU)
#define K2STEP(COMP, KK) { \
  float4 mv = *(const float4*)&m2t[(KK)][4 * sc]; \
  acc[0][0] += wr[0].COMP * mv.x; acc[0][1] += wr[0].COMP * mv.y; acc[0][2] += wr[0].COMP * mv.z; acc[0][3] += wr[0].COMP * mv.w; \
  acc[1][0] += wr[1].COMP * mv.x; acc[1][1] += wr[1].COMP * mv.y; acc[1][2] += wr[1].COMP * mv.z; acc[1][3] += wr[1].COMP * mv.w; \
  acc[2][0] += wr[2].COMP * mv.x; acc[2][1] += wr[2].COMP * mv.y; acc[2][2] += wr[2].COMP * mv.z; acc[2][3] += wr[2].COMP * mv.w; \
  acc[3][0] += wr[3].COMP * mv.x; acc[3][1] += wr[3].COMP * mv.y; acc[3][2] += wr[3].COMP * mv.z; acc[3][3] += wr[3].COMP * mv.w; \
  acc[4][0] += wr[4].COMP * mv.x; acc[4][1] += wr[4].COMP * mv.y; acc[4][2] += wr[4].COMP * mv.z; acc[4][3] += wr[4].COMP * mv.w; \
  acc[5][0] += wr[5].COMP * mv.x; acc[5][1] += wr[5].COMP * mv.y; acc[5][2] += wr[5].COMP * mv.z; acc[5][3] += wr[5].COMP * mv.w; \
  acc[6][0] += wr[6].COMP * mv.x; acc[6][1] += wr[6].COMP * mv.y; acc[6][2] += wr[6].COMP * mv.z; acc[6][3] += wr[6].COMP * mv.w; \
  acc[7][0] += wr[7].COMP * mv.x; acc[7][1] += wr[7].COMP * mv.y; acc[7][2] += wr[7].COMP * mv.z; acc[7][3] += wr[7].COMP * mv.w; }

__global__ __launch_bounds__(256, 4) void k2_logits(const float* __restrict__ we,
                                                 const float* __restrict__ M2,
                                                 const float* __restrict__ corr,
                                                 float* __restrict__ logits,
                                                 float* __restrict__ pmaxb,
                                                 float* __restrict__ psumb) {
  int tid = threadIdx.x;
  int sc = tid & 31;
  int vg = tid >> 5;                // 0..7
  unsigned v0 = (unsigned)blockIdx.x * K2_VT;
  __shared__ float m2t[64][128];    // M2 chunk; reused as partial scratch at the end

  unsigned vrow[8];
  #pragma unroll
  for (int u = 0; u < 8; ++u) {
    unsigned v = v0 + 8 * vg + u;
    vrow[u] = (v < V_ ? v : (V_ - 1)) * 128u;
  }

  float acc[8][4];
  #pragma unroll
  for (int u = 0; u < 8; ++u)
    #pragma unroll
    for (int e = 0; e < 4; ++e) acc[u][e] = 0.f;

  #pragma unroll
  for (int c = 0; c < 2; ++c) {
    __syncthreads();
    #pragma unroll
    for (int it = 0; it < 8; ++it) {
      int idx = it * 256 + tid;
      int kr = idx >> 5;
      int scol = (idx & 31) * 4;
      *(float4*)&m2t[kr][scol] = *(const float4*)&M2[(c * 64 + kr) * 128 + scol];
    }
    __syncthreads();
    #pragma unroll 4
    for (int kc = 0; kc < 64; kc += 4) {
      float4 wr[8];
      #pragma unroll
      for (int u = 0; u < 8; ++u)
        wr[u] = *(const float4*)&we[vrow[u] + (unsigned)(c * 64 + kc)];
      K2STEP(x, kc + 0)
      K2STEP(y, kc + 1)
      K2STEP(z, kc + 2)
      K2STEP(w, kc + 3)
    }
  }

  float lm[4], ls[4], Lst[8][4];
  #pragma unroll
  for (int e = 0; e < 4; ++e) { lm[e] = -INFINITY; ls[e] = 0.f; }
  long vbase = (long)v0 + 8 * vg;
  #pragma unroll
  for (int e = 0; e < 4; ++e) {
    long rbase = (long)(4 * sc + e) * V_ + vbase;
    #pragma unroll
    for (int u = 0; u < 8; ++u) {
      if (vbase + u < V_) {
        float L = acc[u][e] + corr[rbase + u];
        Lst[u][e] = L;
        float nm = fmaxf(lm[e], L);
        ls[e] = ls[e] * __expf(lm[e] - nm) + __expf(L - nm);
        lm[e] = nm;
      }
    }
  }
  #pragma unroll
  for (int u = 0; u < 8; ++u) {
    long v = vbase + u;
    if (v < V_) {
      float4 st = make_float4(Lst[u][0], Lst[u][1], Lst[u][2], Lst[u][3]);
      *(float4*)&logits[v * 128 + 4 * sc] = st;
    }
  }

  __syncthreads();
  float* pmx = (float*)m2t;         // [8][128]
  float* psm = pmx + 8 * 128;
  #pragma unroll
  for (int e = 0; e < 4; ++e) {
    pmx[vg * 128 + 4 * sc + e] = lm[e];
    psm[vg * 128 + 4 * sc + e] = ls[e];
  }
  __syncthreads();
  if (tid < 128) {
    int s = tid;
    float m = -INFINITY, sum = 0.f;
    #pragma unroll
    for (int g = 0; g < 8; ++g) {
      float pm = pmx[g * 128 + s];
      if (pm > -1e30f) {
        float ps = psm[g * 128 + s];
        float nm = fmaxf(m, pm);
        sum = sum * __expf(m - nm) + ps * __expf(pm - nm);
        m = nm;
      }
    }
    pmaxb[blockIdx.x * 128 + s] = m;
    psumb[blockIdx.x * 128 + s] = sum;
  }
}

// ---------------- k3: reduce per-block partials -> C[s] ----------------
__global__ __launch_bounds__(256) void k3_c(const float* __restrict__ pmaxb,
                                            const float* __restrict__ psumb,
                                            float* __restrict__ C) {
  int s = blockIdx.x;
  int t = threadIdx.x;
  float m = -INFINITY, sum = 0.f;
  #pragma unroll
  for (int q = 0; q < 4; ++q) {
    int b = t + q * 256;
    if (b < K2_NB) {
      float pm = pmaxb[b * 128 + s];
      if (pm > -1e30f) {
        float ps = psumb[b * 128 + s];
        float nm = fmaxf(m, pm);
        sum = sum * __expf(m - nm) + ps * __expf(pm - nm);
        m = nm;
      }
    }
  }
  #pragma unroll
  for (int off = 32; off; off >>= 1) {
    float om = __shfl_xor(m, off);
    float os = __shfl_xor(sum, off);
    float nm = fmaxf(m, om);
    sum = sum * __expf(m - nm) + os * __expf(om - nm);
    m = nm;
  }
  __shared__ float wm[4], wsv[4];
  int lane = t & 63, wv = t >> 6;
  if (lane == 0) { wm[wv] = m; wsv[wv] = sum; }
  __syncthreads();
  if (t == 0) {
    float M = fmaxf(fmaxf(wm[0], wm[1]), fmaxf(wm[2], wm[3]));
    float S = wsv[0] * __expf(wm[0] - M) + wsv[1] * __expf(wm[1] - M)
            + wsv[2] * __expf(wm[2] - M) + wsv[3] * __expf(wm[3] - M);
    C[s] = M + __logf(S);
  }
}

// ---------------- k4: forward recurrence (R11 + A-phase load balancing) ----------------
// 512 threads: j = tid&127 (state), h = tid>>7 (i-range [32h,32h+32)).
// R10/R11 showed the wall is barrier-arrival skew + arbitration (prio gave -17us).
// This round rebalances phase A so the B-executing waves are no longer stragglers:
// (1) slice-max DELETED -- Mst computed by 6-step shfl butterfly over fresh `a` at
//     the end of B, parity-buffered in wredM[2][2] (fmax assoc/comm -> bit-identical);
// (2) em pipeline (logits prefetch + exp) moved from waves 0-1 to waves 4-5, which
//     write em_lds[j] at the top of phase A (single buffer: B(t-1) read / barrier /
//     A(t) write / barrier / B(t) read -- no race). Same formula, same inputs.
// Waves 0-1 A = pure dot. Prio: waves 0-1 and 4-5 baseline 1, B escalates to 2.
__global__ __launch_bounds__(512, 4) void k4_rec(const int* __restrict__ words,
                                              const float* __restrict__ masks,
                                              const float* __restrict__ A,
                                              const float* __restrict__ C,
                                              const float* __restrict__ logits,
                                              float* __restrict__ bv) {
  const float kB = 70.70101247f;     // 102*ln2, pairs with 0x1p102f
  int tid = threadIdx.x;
  int j = tid & 127;
  int h = tid >> 7;                  // 0..3
  int b = blockIdx.x;
  int lane = tid & 63, w = tid >> 6;
  __shared__ __align__(16) float els[128];
  __shared__ float part[4][128];
  __shared__ float wredM[2][2];      // parity-buffered cross-wave max (waves 0-1)
  __shared__ float wred[2];
  __shared__ float em_lds[128];      // em for current step, written by waves 4-5
  __shared__ int   wbuf[128];
  __shared__ float mbuf[128];
  if (tid < 128) {
    wbuf[j] = words[j * B_ + b];
    mbuf[j] = masks[j * B_ + b];
  }
  float Ac[32];
  #pragma unroll
  for (int k = 0; k < 32; ++k) Ac[k] = A[(h * 32 + k) * 128 + j];
  __syncthreads();

  if (h == 0 || h == 2) __builtin_amdgcn_s_setprio(1);  // critical-path waves

  float a = 0.f, S = 0.f, Cj = 0.f, a0 = 0.f;
  float Lc = 0.f, Cj2 = 0.f;         // em-pipeline state (waves 4-5)
  if (tid < 128) {
    Cj = C[j];
    a0 = -4.852030263919617f + logits[(unsigned)(wbuf[0] * 128 + j)] - Cj;
    float wm = a0;
    #pragma unroll
    for (int off = 32; off; off >>= 1) wm = fmaxf(wm, __shfl_xor(wm, off));
    if (lane == 0) wred[w] = wm;
  }
  if (h == 2) {                      // waves 4-5 own the em pipeline
    Cj2 = C[j];
    Lc = logits[(unsigned)(wbuf[1] * 128 + j)];
  }
  __syncthreads();
  if (tid < 128) {
    float M0 = fmaxf(wred[0], wred[1]);
    a = __expf(a0 - M0);
    S = M0;
    els[j] = a;
    float wx = a;                    // Mst seed for t=1 (butterfly, exact fmax)
    #pragma unroll
    for (int off = 32; off; off >>= 1) wx = fmaxf(wx, __shfl_xor(wx, off));
    if (lane == 0) wredM[0][w] = wx;
  }
  __syncthreads();

  for (int t = 1; t < T_; ++t) {
    // ---- phase A ----
    if (h == 2) {                    // em for step t + prefetch L(t+1)
      em_lds[j] = __expf(Lc - Cj2 + kB);
      if (t + 1 < T_) Lc = logits[(unsigned)(wbuf[t + 1] * 128 + j)];
    }
    float4 e0 = ((const float4*)els)[h * 8 + 0];
    float4 e1 = ((const float4*)els)[h * 8 + 1];
    float4 e2 = ((const float4*)els)[h * 8 + 2];
    float4 e3 = ((const float4*)els)[h * 8 + 3];
    float4 e4 = ((const float4*)els)[h * 8 + 4];
    float4 e5 = ((const float4*)els)[h * 8 + 5];
    float4 e6 = ((const float4*)els)[h * 8 + 6];
    float4 e7 = ((const float4*)els)[h * 8 + 7];
    float p0 = e0.x * Ac[0]  + e0.y * Ac[1]  + e0.z * Ac[2]  + e0.w * Ac[3]
             + e1.x * Ac[4]  + e1.y * Ac[5]  + e1.z * Ac[6]  + e1.w * Ac[7];
    float p1 = e2.x * Ac[8]  + e2.y * Ac[9]  + e2.z * Ac[10] + e2.w * Ac[11]
             + e3.x * Ac[12] + e3.y * Ac[13] + e3.z * Ac[14] + e3.w * Ac[15];
    float p2 = e4.x * Ac[16] + e4.y * Ac[17] + e4.z * Ac[18] + e4.w * Ac[19]
             + e5.x * Ac[20] + e5.y * Ac[21] + e5.z * Ac[22] + e5.w * Ac[23];
    float p3 = e6.x * Ac[24] + e6.y * Ac[25] + e6.z * Ac[26] + e6.w * Ac[27]
             + e7.x * Ac[28] + e7.y * Ac[29] + e7.z * Ac[30] + e7.w * Ac[31];
    part[h][j] = (p0 + p1) + (p2 + p3);
    __syncthreads();
    // ---- phase B: combine + update (waves 0-1), escalated priority ----
    if (tid < 128) {
      __builtin_amdgcn_s_setprio(2);
      float Mst = fmaxf(wredM[(t + 1) & 1][0], wredM[(t + 1) & 1][1]);
      float invM = 1.f / Mst;
      float P = (part[0][j] + part[1][j]) + (part[2][j] + part[3][j]);
      float emv = em_lds[j];
      float mm = mbuf[t];
      float nv   = (P * invM) * emv;
      float oldq = (a * invM) * 0x1p102f;
      a = mm * nv + (1.f - mm) * oldq;
      els[j] = a;
      S += __logf(Mst) - kB;
      float wx = a;                  // next step's Mst (butterfly, exact)
      #pragma unroll
      for (int off = 32; off; off >>= 1) wx = fmaxf(wx, __shfl_xor(wx, off));
      if (lane == 0) wredM[t & 1][w] = wx;
      __builtin_amdgcn_s_setprio(1);
    }
    __syncthreads();
  }

  if (tid < 128) {
    float ss = a;
    #pragma unroll
    for (int off = 32; off; off >>= 1) ss += __shfl_xor(ss, off);
    if (lane == 0) wred[w] = ss;
  }
  __syncthreads();
  if (tid == 0) bv[b] = S + __logf(wred[0] + wred[1]);
}

// ---------------- k5: out = -sum_b bv[b] ----------------
__global__ __launch_bounds__(256) void k5_sum(const float* __restrict__ bv,
                                              float* __restrict__ out) {
  int t = threadIdx.x;
  float s = bv[t] + bv[t + 256];
  #pragma unroll
  for (int off = 32; off; off >>= 1) s += __shfl_xor(s, off);
  __shared__ float wsm[4];
  if ((t & 63) == 0) wsm[t >> 6] = s;
  __syncthreads();
  if (t == 0) out[0] = -(wsm[0] + wsm[1] + wsm[2] + wsm[3]);
}

extern "C" void kernel_launch(void* const* d_in, const int* in_sizes, int n_in,
                              void* d_out, int out_size, void* d_ws, size_t ws_size,
                              hipStream_t stream) {
  const int*   words      = (const int*)d_in[0];
  const float* masks      = (const float*)d_in[1];
  const float* tparams    = (const float*)d_in[2];
  const float* tag_embed  = (const float*)d_in[3];
  const float* word_embed = (const float*)d_in[4];
  const float* transform  = (const float*)d_in[5];
  const float* correction = (const float*)d_in[6];

  float* ws     = (float*)d_ws;
  float* M2     = ws;                 // 16384
  float* A      = ws + 16384;         // 16384
  float* C      = ws + 32768;         // 128
  float* bv     = ws + 32896;         // 512
  float* pmaxb  = ws + 33408;         // 786*128 = 100608
  float* psumb  = ws + 134016;        // 100608
  float* logits = ws + 234624;        // 6432896  (total ~26.7 MB)

  hipLaunchKernelGGL(k1_fused, dim3(256),    dim3(128), 0, stream, transform, tag_embed, tparams, M2, A);
  hipLaunchKernelGGL(k2_logits,dim3(K2_NB),  dim3(256), 0, stream, word_embed, M2, correction, logits, pmaxb, psumb);
  hipLaunchKernelGGL(k3_c,     dim3(S_),     dim3(256), 0, stream, pmaxb, psumb, C);
  hipLaunchKernelGGL(k4_rec,   dim3(512),    dim3(512), 0, stream, words, masks, A, C, logits, bv);
  hipLaunchKernelGGL(k5_sum,   dim3(1),      dim3(256), 0, stream, bv, (float*)d_out);
}

// Round 13
// 170.235 us; speedup vs baseline: 1.0912x; 1.0912x over previous
//
#include <hip/hip_runtime.h>
#include <math.h>

#define T_ 128
#define B_ 512
#define S_ 128
#define D_ 128
#define V_ 50257

#define K2_VT 64
#define K2_NB ((V_ + K2_VT - 1) / K2_VT)   // 786

// ---------------- k1f: fused {M2 = transform @ tag_embed^T} and {A = softmax(tparams)} ----
__global__ __launch_bounds__(128) void k1_fused(const float* __restrict__ transform,
                                                const float* __restrict__ tag_embed,
                                                const float* __restrict__ tparams,
                                                float* __restrict__ M2,
                                                float* __restrict__ A) {
  int tid = threadIdx.x;
  int bid = blockIdx.x;
  if (bid < 128) {
    __shared__ float te[128][129];
    for (int r = 0; r < 128; ++r) te[r][tid] = tag_embed[r * 128 + tid];
    __syncthreads();
    int k = bid;
    float acc = 0.f;
    #pragma unroll 8
    for (int d = 0; d < 128; ++d) acc += transform[k * 128 + d] * te[tid][d];
    M2[k * 128 + tid] = acc;
  } else {
    if (tid < 64) {
      int i = bid - 128;
      int l = tid;
      float x0 = tparams[i * 128 + l];
      float x1 = tparams[i * 128 + 64 + l];
      float m = fmaxf(x0, x1);
      #pragma unroll
      for (int off = 32; off; off >>= 1) m = fmaxf(m, __shfl_xor(m, off));
      float e0 = __expf(x0 - m), e1 = __expf(x1 - m);
      float s = e0 + e1;
      #pragma unroll
      for (int off = 32; off; off >>= 1) s += __shfl_xor(s, off);
      float inv = 1.f / s;
      A[i * 128 + l]      = e0 * inv;
      A[i * 128 + 64 + l] = e1 * inv;
    }
  }
}

// ---------------- k2: logits = we @ M2 + corr^T, fused col-softmax partials ----------------
// (round-8 v2: no weT tile, m2t-only LDS, 4 blocks/CU)
#define K2STEP(COMP, KK) { \
  float4 mv = *(const float4*)&m2t[(KK)][4 * sc]; \
  acc[0][0] += wr[0].COMP * mv.x; acc[0][1] += wr[0].COMP * mv.y; acc[0][2] += wr[0].COMP * mv.z; acc[0][3] += wr[0].COMP * mv.w; \
  acc[1][0] += wr[1].COMP * mv.x; acc[1][1] += wr[1].COMP * mv.y; acc[1][2] += wr[1].COMP * mv.z; acc[1][3] += wr[1].COMP * mv.w; \
  acc[2][0] += wr[2].COMP * mv.x; acc[2][1] += wr[2].COMP * mv.y; acc[2][2] += wr[2].COMP * mv.z; acc[2][3] += wr[2].COMP * mv.w; \
  acc[3][0] += wr[3].COMP * mv.x; acc[3][1] += wr[3].COMP * mv.y; acc[3][2] += wr[3].COMP * mv.z; acc[3][3] += wr[3].COMP * mv.w; \
  acc[4][0] += wr[4].COMP * mv.x; acc[4][1] += wr[4].COMP * mv.y; acc[4][2] += wr[4].COMP * mv.z; acc[4][3] += wr[4].COMP * mv.w; \
  acc[5][0] += wr[5].COMP * mv.x; acc[5][1] += wr[5].COMP * mv.y; acc[5][2] += wr[5].COMP * mv.z; acc[5][3] += wr[5].COMP * mv.w; \
  acc[6][0] += wr[6].COMP * mv.x; acc[6][1] += wr[6].COMP * mv.y; acc[6][2] += wr[6].COMP * mv.z; acc[6][3] += wr[6].COMP * mv.w; \
  acc[7][0] += wr[7].COMP * mv.x; acc[7][1] += wr[7].COMP * mv.y; acc[7][2] += wr[7].COMP * mv.z; acc[7][3] += wr[7].COMP * mv.w; }

__global__ __launch_bounds__(256, 4) void k2_logits(const float* __restrict__ we,
                                                 const float* __restrict__ M2,
                                                 const float* __restrict__ corr,
                                                 float* __restrict__ logits,
                                                 float* __restrict__ pmaxb,
                                                 float* __restrict__ psumb) {
  int tid = threadIdx.x;
  int sc = tid & 31;
  int vg = tid >> 5;                // 0..7
  unsigned v0 = (unsigned)blockIdx.x * K2_VT;
  __shared__ float m2t[64][128];    // M2 chunk; reused as partial scratch at the end

  unsigned vrow[8];
  #pragma unroll
  for (int u = 0; u < 8; ++u) {
    unsigned v = v0 + 8 * vg + u;
    vrow[u] = (v < V_ ? v : (V_ - 1)) * 128u;
  }

  float acc[8][4];
  #pragma unroll
  for (int u = 0; u < 8; ++u)
    #pragma unroll
    for (int e = 0; e < 4; ++e) acc[u][e] = 0.f;

  #pragma unroll
  for (int c = 0; c < 2; ++c) {
    __syncthreads();
    #pragma unroll
    for (int it = 0; it < 8; ++it) {
      int idx = it * 256 + tid;
      int kr = idx >> 5;
      int scol = (idx & 31) * 4;
      *(float4*)&m2t[kr][scol] = *(const float4*)&M2[(c * 64 + kr) * 128 + scol];
    }
    __syncthreads();
    #pragma unroll 4
    for (int kc = 0; kc < 64; kc += 4) {
      float4 wr[8];
      #pragma unroll
      for (int u = 0; u < 8; ++u)
        wr[u] = *(const float4*)&we[vrow[u] + (unsigned)(c * 64 + kc)];
      K2STEP(x, kc + 0)
      K2STEP(y, kc + 1)
      K2STEP(z, kc + 2)
      K2STEP(w, kc + 3)
    }
  }

  float lm[4], ls[4], Lst[8][4];
  #pragma unroll
  for (int e = 0; e < 4; ++e) { lm[e] = -INFINITY; ls[e] = 0.f; }
  long vbase = (long)v0 + 8 * vg;
  #pragma unroll
  for (int e = 0; e < 4; ++e) {
    long rbase = (long)(4 * sc + e) * V_ + vbase;
    #pragma unroll
    for (int u = 0; u < 8; ++u) {
      if (vbase + u < V_) {
        float L = acc[u][e] + corr[rbase + u];
        Lst[u][e] = L;
        float nm = fmaxf(lm[e], L);
        ls[e] = ls[e] * __expf(lm[e] - nm) + __expf(L - nm);
        lm[e] = nm;
      }
    }
  }
  #pragma unroll
  for (int u = 0; u < 8; ++u) {
    long v = vbase + u;
    if (v < V_) {
      float4 st = make_float4(Lst[u][0], Lst[u][1], Lst[u][2], Lst[u][3]);
      *(float4*)&logits[v * 128 + 4 * sc] = st;
    }
  }

  __syncthreads();
  float* pmx = (float*)m2t;         // [8][128]
  float* psm = pmx + 8 * 128;
  #pragma unroll
  for (int e = 0; e < 4; ++e) {
    pmx[vg * 128 + 4 * sc + e] = lm[e];
    psm[vg * 128 + 4 * sc + e] = ls[e];
  }
  __syncthreads();
  if (tid < 128) {
    int s = tid;
    float m = -INFINITY, sum = 0.f;
    #pragma unroll
    for (int g = 0; g < 8; ++g) {
      float pm = pmx[g * 128 + s];
      if (pm > -1e30f) {
        float ps = psm[g * 128 + s];
        float nm = fmaxf(m, pm);
        sum = sum * __expf(m - nm) + ps * __expf(pm - nm);
        m = nm;
      }
    }
    pmaxb[blockIdx.x * 128 + s] = m;
    psumb[blockIdx.x * 128 + s] = sum;
  }
}

// ---------------- k3: reduce per-block partials -> C[s] ----------------
__global__ __launch_bounds__(256) void k3_c(const float* __restrict__ pmaxb,
                                            const float* __restrict__ psumb,
                                            float* __restrict__ C) {
  int s = blockIdx.x;
  int t = threadIdx.x;
  float m = -INFINITY, sum = 0.f;
  #pragma unroll
  for (int q = 0; q < 4; ++q) {
    int b = t + q * 256;
    if (b < K2_NB) {
      float pm = pmaxb[b * 128 + s];
      if (pm > -1e30f) {
        float ps = psumb[b * 128 + s];
        float nm = fmaxf(m, pm);
        sum = sum * __expf(m - nm) + ps * __expf(pm - nm);
        m = nm;
      }
    }
  }
  #pragma unroll
  for (int off = 32; off; off >>= 1) {
    float om = __shfl_xor(m, off);
    float os = __shfl_xor(sum, off);
    float nm = fmaxf(m, om);
    sum = sum * __expf(m - nm) + os * __expf(om - nm);
    m = nm;
  }
  __shared__ float wm[4], wsv[4];
  int lane = t & 63, wv = t >> 6;
  if (lane == 0) { wm[wv] = m; wsv[wv] = sum; }
  __syncthreads();
  if (t == 0) {
    float M = fmaxf(fmaxf(wm[0], wm[1]), fmaxf(wm[2], wm[3]));
    float S = wsv[0] * __expf(wm[0] - M) + wsv[1] * __expf(wm[1] - M)
            + wsv[2] * __expf(wm[2] - M) + wsv[3] * __expf(wm[3] - M);
    C[s] = M + __logf(S);
  }
}

// ---------------- k4: per-batch forward recurrence (R11 structure, phase-B prio 3) ----
// EXACT revert to the round-11 kernel (105.4 us best: slice-max in phase A by j==0
// lanes, em pipeline register-resident in waves 0-1, waves 0-1 baseline prio 1)
// with ONE change: phase-B escalation 2 -> 3. R12's "balancing" (butterfly in B,
// em via LDS) lengthened B's serial chain + made waves 4-5 stragglers: +13 us.
// Rule learned: never add work to the critical waves; only arbitration is free.
__global__ __launch_bounds__(512, 4) void k4_rec(const int* __restrict__ words,
                                              const float* __restrict__ masks,
                                              const float* __restrict__ A,
                                              const float* __restrict__ C,
                                              const float* __restrict__ logits,
                                              float* __restrict__ bv) {
  const float kB = 70.70101247f;     // 102*ln2, pairs with 0x1p102f
  int tid = threadIdx.x;
  int j = tid & 127;
  int h = tid >> 7;                  // 0..3
  int b = blockIdx.x;
  int lane = tid & 63, w = tid >> 6;
  __shared__ __align__(16) float els[128];
  __shared__ float part[4][128];
  __shared__ __align__(16) float pmax4[4];
  __shared__ float wred[2];
  __shared__ int   wbuf[128];
  __shared__ float mbuf[128];
  if (tid < 128) {
    wbuf[j] = words[j * B_ + b];
    mbuf[j] = masks[j * B_ + b];
  }
  float Ac[32];
  #pragma unroll
  for (int k = 0; k < 32; ++k) Ac[k] = A[(h * 32 + k) * 128 + j];
  __syncthreads();

  float a = 0.f, S = 0.f, em_cur = 0.f, Lnext = 0.f, Cj = 0.f, a0 = 0.f;
  if (tid < 128) {
    __builtin_amdgcn_s_setprio(1);   // critical waves: baseline priority for the kernel
    Cj = C[j];
    a0 = -4.852030263919617f + logits[(unsigned)(wbuf[0] * 128 + j)] - Cj;
    float wm = a0;
    #pragma unroll
    for (int off = 32; off; off >>= 1) wm = fmaxf(wm, __shfl_xor(wm, off));
    if (lane == 0) wred[w] = wm;
  }
  __syncthreads();
  if (tid < 128) {
    float M0 = fmaxf(wred[0], wred[1]);
    a = __expf(a0 - M0);
    S = M0;
    els[j] = a;
    float L1 = logits[(unsigned)(wbuf[1] * 128 + j)];
    Lnext    = logits[(unsigned)(wbuf[2] * 128 + j)];
    em_cur = __expf(L1 - Cj + kB);
  }
  __syncthreads();

  for (int t = 1; t < T_; ++t) {
    // ---- phase A: dot + slice-max (all), prefetch/exp off-path (tid<128) ----
    float4 e0 = ((const float4*)els)[h * 8 + 0];
    float4 e1 = ((const float4*)els)[h * 8 + 1];
    float4 e2 = ((const float4*)els)[h * 8 + 2];
    float4 e3 = ((const float4*)els)[h * 8 + 3];
    float4 e4 = ((const float4*)els)[h * 8 + 4];
    float4 e5 = ((const float4*)els)[h * 8 + 5];
    float4 e6 = ((const float4*)els)[h * 8 + 6];
    float4 e7 = ((const float4*)els)[h * 8 + 7];
    float p0 = e0.x * Ac[0]  + e0.y * Ac[1]  + e0.z * Ac[2]  + e0.w * Ac[3]
             + e1.x * Ac[4]  + e1.y * Ac[5]  + e1.z * Ac[6]  + e1.w * Ac[7];
    float p1 = e2.x * Ac[8]  + e2.y * Ac[9]  + e2.z * Ac[10] + e2.w * Ac[11]
             + e3.x * Ac[12] + e3.y * Ac[13] + e3.z * Ac[14] + e3.w * Ac[15];
    float p2 = e4.x * Ac[16] + e4.y * Ac[17] + e4.z * Ac[18] + e4.w * Ac[19]
             + e5.x * Ac[20] + e5.y * Ac[21] + e5.z * Ac[22] + e5.w * Ac[23];
    float p3 = e6.x * Ac[24] + e6.y * Ac[25] + e6.z * Ac[26] + e6.w * Ac[27]
             + e7.x * Ac[28] + e7.y * Ac[29] + e7.z * Ac[30] + e7.w * Ac[31];
    part[h][j] = (p0 + p1) + (p2 + p3);
    if (j == 0) {                    // only 4 lanes pay for the slice-max
      float4 ma = make_float4(fmaxf(e0.x, e1.x), fmaxf(e0.y, e1.y), fmaxf(e0.z, e1.z), fmaxf(e0.w, e1.w));
      float4 mb = make_float4(fmaxf(e2.x, e3.x), fmaxf(e2.y, e3.y), fmaxf(e2.z, e3.z), fmaxf(e2.w, e3.w));
      float4 mc = make_float4(fmaxf(e4.x, e5.x), fmaxf(e4.y, e5.y), fmaxf(e4.z, e5.z), fmaxf(e4.w, e5.w));
      float4 md = make_float4(fmaxf(e6.x, e7.x), fmaxf(e6.y, e7.y), fmaxf(e6.z, e7.z), fmaxf(e6.w, e7.w));
      float4 m1 = make_float4(fmaxf(ma.x, mb.x), fmaxf(ma.y, mb.y), fmaxf(ma.z, mb.z), fmaxf(ma.w, mb.w));
      float4 m2 = make_float4(fmaxf(mc.x, md.x), fmaxf(mc.y, md.y), fmaxf(mc.z, md.z), fmaxf(mc.w, md.w));
      float mx = fmaxf(fmaxf(fmaxf(m1.x, m1.y), fmaxf(m1.z, m1.w)),
                       fmaxf(fmaxf(m2.x, m2.y), fmaxf(m2.z, m2.w)));
      pmax4[h] = mx;
    }
    float em_next = 0.f, Lf = 0.f;
    if (tid < 128) {
      if (t + 2 < T_) Lf = logits[(unsigned)(wbuf[t + 2] * 128 + j)];
      em_next = __expf(Lnext - Cj + kB);
    }
    __syncthreads();
    // ---- phase B: combine + update (tid<128), max escalation ----
    if (tid < 128) {
      __builtin_amdgcn_s_setprio(3);
      float4 pm4 = *(const float4*)pmax4;
      float Mst = fmaxf(fmaxf(pm4.x, pm4.y), fmaxf(pm4.z, pm4.w));
      float invM = 1.f / Mst;
      float P = (part[0][j] + part[1][j]) + (part[2][j] + part[3][j]);
      float nv   = (P * invM) * em_cur;
      float oldq = (a * invM) * 0x1p102f;
      float mm = mbuf[t];
      a = mm * nv + (1.f - mm) * oldq;
      els[j] = a;
      S += __logf(Mst) - kB;
      em_cur = em_next;
      Lnext = Lf;
      __builtin_amdgcn_s_setprio(1); // back to elevated baseline
    }
    __syncthreads();
  }

  if (tid < 128) {
    float ss = a;
    #pragma unroll
    for (int off = 32; off; off >>= 1) ss += __shfl_xor(ss, off);
    if (lane == 0) wred[w] = ss;
  }
  __syncthreads();
  if (tid == 0) bv[b] = S + __logf(wred[0] + wred[1]);
}

// ---------------- k5: out = -sum_b bv[b] ----------------
__global__ __launch_bounds__(256) void k5_sum(const float* __restrict__ bv,
                                              float* __restrict__ out) {
  int t = threadIdx.x;
  float s = bv[t] + bv[t + 256];
  #pragma unroll
  for (int off = 32; off; off >>= 1) s += __shfl_xor(s, off);
  __shared__ float wsm[4];
  if ((t & 63) == 0) wsm[t >> 6] = s;
  __syncthreads();
  if (t == 0) out[0] = -(wsm[0] + wsm[1] + wsm[2] + wsm[3]);
}

extern "C" void kernel_launch(void* const* d_in, const int* in_sizes, int n_in,
                              void* d_out, int out_size, void* d_ws, size_t ws_size,
                              hipStream_t stream) {
  const int*   words      = (const int*)d_in[0];
  const float* masks      = (const float*)d_in[1];
  const float* tparams    = (const float*)d_in[2];
  const float* tag_embed  = (const float*)d_in[3];
  const float* word_embed = (const float*)d_in[4];
  const float* transform  = (const float*)d_in[5];
  const float* correction = (const float*)d_in[6];

  float* ws     = (float*)d_ws;
  float* M2     = ws;                 // 16384
  float* A      = ws + 16384;         // 16384
  float* C      = ws + 32768;         // 128
  float* bv     = ws + 32896;         // 512
  float* pmaxb  = ws + 33408;         // 786*128 = 100608
  float* psumb  = ws + 134016;        // 100608
  float* logits = ws + 234624;        // 6432896  (total ~26.7 MB)

  hipLaunchKernelGGL(k1_fused, dim3(256),    dim3(128), 0, stream, transform, tag_embed, tparams, M2, A);
  hipLaunchKernelGGL(k2_logits,dim3(K2_NB),  dim3(256), 0, stream, word_embed, M2, correction, logits, pmaxb, psumb);
  hipLaunchKernelGGL(k3_c,     dim3(S_),     dim3(256), 0, stream, pmaxb, psumb, C);
  hipLaunchKernelGGL(k4_rec,   dim3(512),    dim3(512), 0, stream, words, masks, A, C, logits, bv);
  hipLaunchKernelGGL(k5_sum,   dim3(1),      dim3(256), 0, stream, bv, (float*)d_out);
}

// Round 14
// 167.147 us; speedup vs baseline: 1.1114x; 1.0185x over previous
//
#include <hip/hip_runtime.h>
#include <math.h>

#define T_ 128
#define B_ 512
#define S_ 128
#define D_ 128
#define V_ 50257

#define K2_VT 64
#define K2_NB ((V_ + K2_VT - 1) / K2_VT)   // 786

// ---------------- k1f: fused {M2 = transform @ tag_embed^T} and {A = softmax(tparams)} ----
__global__ __launch_bounds__(128) void k1_fused(const float* __restrict__ transform,
                                                const float* __restrict__ tag_embed,
                                                const float* __restrict__ tparams,
                                                float* __restrict__ M2,
                                                float* __restrict__ A) {
  int tid = threadIdx.x;
  int bid = blockIdx.x;
  if (bid < 128) {
    __shared__ float te[128][129];
    for (int r = 0; r < 128; ++r) te[r][tid] = tag_embed[r * 128 + tid];
    __syncthreads();
    int k = bid;
    float acc = 0.f;
    #pragma unroll 8
    for (int d = 0; d < 128; ++d) acc += transform[k * 128 + d] * te[tid][d];
    M2[k * 128 + tid] = acc;
  } else {
    if (tid < 64) {
      int i = bid - 128;
      int l = tid;
      float x0 = tparams[i * 128 + l];
      float x1 = tparams[i * 128 + 64 + l];
      float m = fmaxf(x0, x1);
      #pragma unroll
      for (int off = 32; off; off >>= 1) m = fmaxf(m, __shfl_xor(m, off));
      float e0 = __expf(x0 - m), e1 = __expf(x1 - m);
      float s = e0 + e1;
      #pragma unroll
      for (int off = 32; off; off >>= 1) s += __shfl_xor(s, off);
      float inv = 1.f / s;
      A[i * 128 + l]      = e0 * inv;
      A[i * 128 + 64 + l] = e1 * inv;
    }
  }
}

// ---------------- k2: logits = we @ M2 + corr^T, fused col-softmax partials ----------------
// v3: corr epilogue read STAGED through LDS with coalesced loads. The old direct
// read (4 rows x 8 floats per lane at 201KB row stride) used 32B per 128B line on
// single-use data -> ~4x HBM overfetch (~100MB, ~16us) + exposed latency. Now each
// block stages its corr tile [128][64] (32KB) into LDS reusing m2t's space (union,
// pitch 65 -> 4-way max bank conflict on the once-only epilogue read). Same values
// added in the same order -> logits/pmaxb/psumb bit-identical.
#define K2STEP(COMP, KK) { \
  float4 mv = *(const float4*)&m2t[(KK)][4 * sc]; \
  acc[0][0] += wr[0].COMP * mv.x; acc[0][1] += wr[0].COMP * mv.y; acc[0][2] += wr[0].COMP * mv.z; acc[0][3] += wr[0].COMP * mv.w; \
  acc[1][0] += wr[1].COMP * mv.x; acc[1][1] += wr[1].COMP * mv.y; acc[1][2] += wr[1].COMP * mv.z; acc[1][3] += wr[1].COMP * mv.w; \
  acc[2][0] += wr[2].COMP * mv.x; acc[2][1] += wr[2].COMP * mv.y; acc[2][2] += wr[2].COMP * mv.z; acc[2][3] += wr[2].COMP * mv.w; \
  acc[3][0] += wr[3].COMP * mv.x; acc[3][1] += wr[3].COMP * mv.y; acc[3][2] += wr[3].COMP * mv.z; acc[3][3] += wr[3].COMP * mv.w; \
  acc[4][0] += wr[4].COMP * mv.x; acc[4][1] += wr[4].COMP * mv.y; acc[4][2] += wr[4].COMP * mv.z; acc[4][3] += wr[4].COMP * mv.w; \
  acc[5][0] += wr[5].COMP * mv.x; acc[5][1] += wr[5].COMP * mv.y; acc[5][2] += wr[5].COMP * mv.z; acc[5][3] += wr[5].COMP * mv.w; \
  acc[6][0] += wr[6].COMP * mv.x; acc[6][1] += wr[6].COMP * mv.y; acc[6][2] += wr[6].COMP * mv.z; acc[6][3] += wr[6].COMP * mv.w; \
  acc[7][0] += wr[7].COMP * mv.x; acc[7][1] += wr[7].COMP * mv.y; acc[7][2] += wr[7].COMP * mv.z; acc[7][3] += wr[7].COMP * mv.w; }

__global__ __launch_bounds__(256, 4) void k2_logits(const float* __restrict__ we,
                                                 const float* __restrict__ M2,
                                                 const float* __restrict__ corr,
                                                 float* __restrict__ logits,
                                                 float* __restrict__ pmaxb,
                                                 float* __restrict__ psumb) {
  int tid = threadIdx.x;
  int sc = tid & 31;
  int vg = tid >> 5;                // 0..7
  unsigned v0 = (unsigned)blockIdx.x * K2_VT;
  __shared__ __align__(16) float smem[128 * 65];   // 33.3 KB union buffer
  float (*m2t)[128] = reinterpret_cast<float(*)[128]>(smem);  // [64][128] main loop
  float (*ct)[65]   = reinterpret_cast<float(*)[65]>(smem);   // [128][65] corr tile

  unsigned vrow[8];
  #pragma unroll
  for (int u = 0; u < 8; ++u) {
    unsigned v = v0 + 8 * vg + u;
    vrow[u] = (v < V_ ? v : (V_ - 1)) * 128u;
  }

  float acc[8][4];
  #pragma unroll
  for (int u = 0; u < 8; ++u)
    #pragma unroll
    for (int e = 0; e < 4; ++e) acc[u][e] = 0.f;

  #pragma unroll
  for (int c = 0; c < 2; ++c) {
    __syncthreads();
    #pragma unroll
    for (int it = 0; it < 8; ++it) {
      int idx = it * 256 + tid;
      int kr = idx >> 5;
      int scol = (idx & 31) * 4;
      *(float4*)&m2t[kr][scol] = *(const float4*)&M2[(c * 64 + kr) * 128 + scol];
    }
    __syncthreads();
    #pragma unroll 4
    for (int kc = 0; kc < 64; kc += 4) {
      float4 wr[8];
      #pragma unroll
      for (int u = 0; u < 8; ++u)
        wr[u] = *(const float4*)&we[vrow[u] + (unsigned)(c * 64 + kc)];
      K2STEP(x, kc + 0)
      K2STEP(y, kc + 1)
      K2STEP(z, kc + 2)
      K2STEP(w, kc + 3)
    }
  }

  // ---- stage corr tile [128 rows][64 cols] coalesced (reuses m2t space) ----
  __syncthreads();                  // main-loop m2t reads done
  #pragma unroll
  for (int it = 0; it < 32; ++it) {
    int f = it * 256 + tid;         // 0..8191
    int row = f >> 6;               // 0..127
    int col = f & 63;
    long v = (long)v0 + col;
    ct[row][col] = (v < V_) ? corr[(long)row * V_ + v] : 0.f;
  }
  __syncthreads();

  // epilogue: + corr (from LDS), online column partials, float4 stores
  float lm[4], ls[4], Lst[8][4];
  #pragma unroll
  for (int e = 0; e < 4; ++e) { lm[e] = -INFINITY; ls[e] = 0.f; }
  long vbase = (long)v0 + 8 * vg;
  #pragma unroll
  for (int e = 0; e < 4; ++e) {
    #pragma unroll
    for (int u = 0; u < 8; ++u) {
      if (vbase + u < V_) {
        float L = acc[u][e] + ct[4 * sc + e][8 * vg + u];
        Lst[u][e] = L;
        float nm = fmaxf(lm[e], L);
        ls[e] = ls[e] * __expf(lm[e] - nm) + __expf(L - nm);
        lm[e] = nm;
      }
    }
  }
  #pragma unroll
  for (int u = 0; u < 8; ++u) {
    long v = vbase + u;
    if (v < V_) {
      float4 st = make_float4(Lst[u][0], Lst[u][1], Lst[u][2], Lst[u][3]);
      *(float4*)&logits[v * 128 + 4 * sc] = st;
    }
  }

  __syncthreads();                  // ct reads done -> reuse as partial scratch
  float* pmx = smem;                // [8][128]
  float* psm = pmx + 8 * 128;
  #pragma unroll
  for (int e = 0; e < 4; ++e) {
    pmx[vg * 128 + 4 * sc + e] = lm[e];
    psm[vg * 128 + 4 * sc + e] = ls[e];
  }
  __syncthreads();
  if (tid < 128) {
    int s = tid;
    float m = -INFINITY, sum = 0.f;
    #pragma unroll
    for (int g = 0; g < 8; ++g) {
      float pm = pmx[g * 128 + s];
      if (pm > -1e30f) {
        float ps = psm[g * 128 + s];
        float nm = fmaxf(m, pm);
        sum = sum * __expf(m - nm) + ps * __expf(pm - nm);
        m = nm;
      }
    }
    pmaxb[blockIdx.x * 128 + s] = m;
    psumb[blockIdx.x * 128 + s] = sum;
  }
}

// ---------------- k3: reduce per-block partials -> C[s] ----------------
__global__ __launch_bounds__(256) void k3_c(const float* __restrict__ pmaxb,
                                            const float* __restrict__ psumb,
                                            float* __restrict__ C) {
  int s = blockIdx.x;
  int t = threadIdx.x;
  float m = -INFINITY, sum = 0.f;
  #pragma unroll
  for (int q = 0; q < 4; ++q) {
    int b = t + q * 256;
    if (b < K2_NB) {
      float pm = pmaxb[b * 128 + s];
      if (pm > -1e30f) {
        float ps = psumb[b * 128 + s];
        float nm = fmaxf(m, pm);
        sum = sum * __expf(m - nm) + ps * __expf(pm - nm);
        m = nm;
      }
    }
  }
  #pragma unroll
  for (int off = 32; off; off >>= 1) {
    float om = __shfl_xor(m, off);
    float os = __shfl_xor(sum, off);
    float nm = fmaxf(m, om);
    sum = sum * __expf(m - nm) + os * __expf(om - nm);
    m = nm;
  }
  __shared__ float wm[4], wsv[4];
  int lane = t & 63, wv = t >> 6;
  if (lane == 0) { wm[wv] = m; wsv[wv] = sum; }
  __syncthreads();
  if (t == 0) {
    float M = fmaxf(fmaxf(wm[0], wm[1]), fmaxf(wm[2], wm[3]));
    float S = wsv[0] * __expf(wm[0] - M) + wsv[1] * __expf(wm[1] - M)
            + wsv[2] * __expf(wm[2] - M) + wsv[3] * __expf(wm[3] - M);
    C[s] = M + __logf(S);
  }
}

// ---------------- k4: per-batch forward recurrence (converged: R11 structure + prio) ----
// 105 us floor, established over rounds 0-13. Do not touch.
__global__ __launch_bounds__(512, 4) void k4_rec(const int* __restrict__ words,
                                              const float* __restrict__ masks,
                                              const float* __restrict__ A,
                                              const float* __restrict__ C,
                                              const float* __restrict__ logits,
                                              float* __restrict__ bv) {
  const float kB = 70.70101247f;     // 102*ln2, pairs with 0x1p102f
  int tid = threadIdx.x;
  int j = tid & 127;
  int h = tid >> 7;                  // 0..3
  int b = blockIdx.x;
  int lane = tid & 63, w = tid >> 6;
  __shared__ __align__(16) float els[128];
  __shared__ float part[4][128];
  __shared__ __align__(16) float pmax4[4];
  __shared__ float wred[2];
  __shared__ int   wbuf[128];
  __shared__ float mbuf[128];
  if (tid < 128) {
    wbuf[j] = words[j * B_ + b];
    mbuf[j] = masks[j * B_ + b];
  }
  float Ac[32];
  #pragma unroll
  for (int k = 0; k < 32; ++k) Ac[k] = A[(h * 32 + k) * 128 + j];
  __syncthreads();

  float a = 0.f, S = 0.f, em_cur = 0.f, Lnext = 0.f, Cj = 0.f, a0 = 0.f;
  if (tid < 128) {
    __builtin_amdgcn_s_setprio(1);   // critical waves: baseline priority for the kernel
    Cj = C[j];
    a0 = -4.852030263919617f + logits[(unsigned)(wbuf[0] * 128 + j)] - Cj;
    float wm = a0;
    #pragma unroll
    for (int off = 32; off; off >>= 1) wm = fmaxf(wm, __shfl_xor(wm, off));
    if (lane == 0) wred[w] = wm;
  }
  __syncthreads();
  if (tid < 128) {
    float M0 = fmaxf(wred[0], wred[1]);
    a = __expf(a0 - M0);
    S = M0;
    els[j] = a;
    float L1 = logits[(unsigned)(wbuf[1] * 128 + j)];
    Lnext    = logits[(unsigned)(wbuf[2] * 128 + j)];
    em_cur = __expf(L1 - Cj + kB);
  }
  __syncthreads();

  for (int t = 1; t < T_; ++t) {
    // ---- phase A: dot + slice-max (all), prefetch/exp off-path (tid<128) ----
    float4 e0 = ((const float4*)els)[h * 8 + 0];
    float4 e1 = ((const float4*)els)[h * 8 + 1];
    float4 e2 = ((const float4*)els)[h * 8 + 2];
    float4 e3 = ((const float4*)els)[h * 8 + 3];
    float4 e4 = ((const float4*)els)[h * 8 + 4];
    float4 e5 = ((const float4*)els)[h * 8 + 5];
    float4 e6 = ((const float4*)els)[h * 8 + 6];
    float4 e7 = ((const float4*)els)[h * 8 + 7];
    float p0 = e0.x * Ac[0]  + e0.y * Ac[1]  + e0.z * Ac[2]  + e0.w * Ac[3]
             + e1.x * Ac[4]  + e1.y * Ac[5]  + e1.z * Ac[6]  + e1.w * Ac[7];
    float p1 = e2.x * Ac[8]  + e2.y * Ac[9]  + e2.z * Ac[10] + e2.w * Ac[11]
             + e3.x * Ac[12] + e3.y * Ac[13] + e3.z * Ac[14] + e3.w * Ac[15];
    float p2 = e4.x * Ac[16] + e4.y * Ac[17] + e4.z * Ac[18] + e4.w * Ac[19]
             + e5.x * Ac[20] + e5.y * Ac[21] + e5.z * Ac[22] + e5.w * Ac[23];
    float p3 = e6.x * Ac[24] + e6.y * Ac[25] + e6.z * Ac[26] + e6.w * Ac[27]
             + e7.x * Ac[28] + e7.y * Ac[29] + e7.z * Ac[30] + e7.w * Ac[31];
    part[h][j] = (p0 + p1) + (p2 + p3);
    if (j == 0) {                    // only 4 lanes pay for the slice-max
      float4 ma = make_float4(fmaxf(e0.x, e1.x), fmaxf(e0.y, e1.y), fmaxf(e0.z, e1.z), fmaxf(e0.w, e1.w));
      float4 mb = make_float4(fmaxf(e2.x, e3.x), fmaxf(e2.y, e3.y), fmaxf(e2.z, e3.z), fmaxf(e2.w, e3.w));
      float4 mc = make_float4(fmaxf(e4.x, e5.x), fmaxf(e4.y, e5.y), fmaxf(e4.z, e5.z), fmaxf(e4.w, e5.w));
      float4 md = make_float4(fmaxf(e6.x, e7.x), fmaxf(e6.y, e7.y), fmaxf(e6.z, e7.z), fmaxf(e6.w, e7.w));
      float4 m1 = make_float4(fmaxf(ma.x, mb.x), fmaxf(ma.y, mb.y), fmaxf(ma.z, mb.z), fmaxf(ma.w, mb.w));
      float4 m2 = make_float4(fmaxf(mc.x, md.x), fmaxf(mc.y, md.y), fmaxf(mc.z, md.z), fmaxf(mc.w, md.w));
      float mx = fmaxf(fmaxf(fmaxf(m1.x, m1.y), fmaxf(m1.z, m1.w)),
                       fmaxf(fmaxf(m2.x, m2.y), fmaxf(m2.z, m2.w)));
      pmax4[h] = mx;
    }
    float em_next = 0.f, Lf = 0.f;
    if (tid < 128) {
      if (t + 2 < T_) Lf = logits[(unsigned)(wbuf[t + 2] * 128 + j)];
      em_next = __expf(Lnext - Cj + kB);
    }
    __syncthreads();
    // ---- phase B: combine + update (tid<128), escalated priority ----
    if (tid < 128) {
      __builtin_amdgcn_s_setprio(3);
      float4 pm4 = *(const float4*)pmax4;
      float Mst = fmaxf(fmaxf(pm4.x, pm4.y), fmaxf(pm4.z, pm4.w));
      float invM = 1.f / Mst;
      float P = (part[0][j] + part[1][j]) + (part[2][j] + part[3][j]);
      float nv   = (P * invM) * em_cur;
      float oldq = (a * invM) * 0x1p102f;
      float mm = mbuf[t];
      a = mm * nv + (1.f - mm) * oldq;
      els[j] = a;
      S += __logf(Mst) - kB;
      em_cur = em_next;
      Lnext = Lf;
      __builtin_amdgcn_s_setprio(1); // back to elevated baseline
    }
    __syncthreads();
  }

  if (tid < 128) {
    float ss = a;
    #pragma unroll
    for (int off = 32; off; off >>= 1) ss += __shfl_xor(ss, off);
    if (lane == 0) wred[w] = ss;
  }
  __syncthreads();
  if (tid == 0) bv[b] = S + __logf(wred[0] + wred[1]);
}

// ---------------- k5: out = -sum_b bv[b] ----------------
__global__ __launch_bounds__(256) void k5_sum(const float* __restrict__ bv,
                                              float* __restrict__ out) {
  int t = threadIdx.x;
  float s = bv[t] + bv[t + 256];
  #pragma unroll
  for (int off = 32; off; off >>= 1) s += __shfl_xor(s, off);
  __shared__ float wsm[4];
  if ((t & 63) == 0) wsm[t >> 6] = s;
  __syncthreads();
  if (t == 0) out[0] = -(wsm[0] + wsm[1] + wsm[2] + wsm[3]);
}

extern "C" void kernel_launch(void* const* d_in, const int* in_sizes, int n_in,
                              void* d_out, int out_size, void* d_ws, size_t ws_size,
                              hipStream_t stream) {
  const int*   words      = (const int*)d_in[0];
  const float* masks      = (const float*)d_in[1];
  const float* tparams    = (const float*)d_in[2];
  const float* tag_embed  = (const float*)d_in[3];
  const float* word_embed = (const float*)d_in[4];
  const float* transform  = (const float*)d_in[5];
  const float* correction = (const float*)d_in[6];

  float* ws     = (float*)d_ws;
  float* M2     = ws;                 // 16384
  float* A      = ws + 16384;         // 16384
  float* C      = ws + 32768;         // 128
  float* bv     = ws + 32896;         // 512
  float* pmaxb  = ws + 33408;         // 786*128 = 100608
  float* psumb  = ws + 134016;        // 100608
  float* logits = ws + 234624;        // 6432896  (total ~26.7 MB)

  hipLaunchKernelGGL(k1_fused, dim3(256),    dim3(128), 0, stream, transform, tag_embed, tparams, M2, A);
  hipLaunchKernelGGL(k2_logits,dim3(K2_NB),  dim3(256), 0, stream, word_embed, M2, correction, logits, pmaxb, psumb);
  hipLaunchKernelGGL(k3_c,     dim3(S_),     dim3(256), 0, stream, pmaxb, psumb, C);
  hipLaunchKernelGGL(k4_rec,   dim3(512),    dim3(512), 0, stream, words, masks, A, C, logits, bv);
  hipLaunchKernelGGL(k5_sum,   dim3(1),      dim3(256), 0, stream, bv, (float*)d_out);
}